// Round 10
// baseline (158.857 us; speedup 1.0000x reference)
//
#include <hip/hip_runtime.h>
#include <hip/hip_bf16.h>
#include <stdint.h>

// STAR-DNN: per-sample scene-selected 3-layer MLP.
// R1: LDS-histogram compaction. R2: global_load_lds DMA. R4 (failed): grid
// barrier ~140us on 8 XCDs. R6 (failed): 135-blk fusion starved CUs.
// R8 (failed): gemm0 at 1 blk/CU latency-bound (MfmaUtil 7.5%).
// R9: gemm0 TM=64/TN=128 grid(270,4) ~4 blk/CU. R10: gemm12 phase-1 BK=32,
// 52KB LDS -> 3 blk/CU (was 2) for more DMA/MFMA cross-block overlap.

#define BATCH   16384
#define NSCENE  7
#define TM      128
#define NBLK    (BATCH / 256)            // 64 count blocks
#define MT_MAX  (BATCH / TM + NSCENE)    // 135 worst-case tiles
#define PADMAX  (BATCH + NSCENE * TM)    // 17280 padded rows max

typedef __bf16 bf16x8 __attribute__((ext_vector_type(8)));
typedef float  f32x4  __attribute__((ext_vector_type(4)));

__device__ __forceinline__ ushort f2bf(float f) {
  union { float f; uint32_t u; } v; v.f = f;
  uint32_t r = (v.u + 0x7FFFu + ((v.u >> 16) & 1u)) >> 16;  // RNE
  return (ushort)r;
}
__device__ __forceinline__ uint32_t pk2(float a, float b) {
  union { __hip_bfloat162 h; uint32_t u; } cv;
  cv.h = __float22bfloat162_rn(make_float2(a, b));   // v_cvt_pk_bf16_f32
  return cv.u;
}
__device__ __forceinline__ void async16(const void* g, void* lds) {
  __builtin_amdgcn_global_load_lds(
      (const __attribute__((address_space(1))) uint32_t*)g,
      (__attribute__((address_space(3))) uint32_t*)lds, 16, 0, 0);
}

// ---- fused prep: W scale+transpose (x3), bias fuse, count+rank -----------
__device__ __forceinline__ void st_tile(const float* __restrict__ W,
                                        const float* __restrict__ gW,
                                        ushort* __restrict__ sT,
                                        int K, int N, int s, int n0, int k0,
                                        int tid) {
  __shared__ float tl[32][33];
  int tx = tid & 31, ty = tid >> 5;
  const float* Wp = W + (size_t)s * K * N;
#pragma unroll
  for (int i = 0; i < 4; i++) {
    int k = k0 + ty + i * 8;
    tl[ty + i * 8][tx] = Wp[(size_t)k * N + n0 + tx] * gW[(size_t)k * N + n0 + tx];
  }
  __syncthreads();
#pragma unroll
  for (int i = 0; i < 4; i++) {
    int n = n0 + ty + i * 8;
    sT[((size_t)s * N + n) * K + k0 + tx] = f2bf(tl[tx][ty + i * 8]);
  }
}

#define NB_W0 (16 * 16 * 7)
#define NB_W1 (8 * 16 * 7)
#define NB_W2 (2 * 8 * 7)
#define NB_BIAS 23
#define NB_CNT NBLK

__global__ __launch_bounds__(256) void prep_k(
    const float* __restrict__ W0, const float* __restrict__ gW0,
    const float* __restrict__ W1, const float* __restrict__ gW1,
    const float* __restrict__ W2, const float* __restrict__ gW2,
    const float* __restrict__ b0, const float* __restrict__ gb0,
    const float* __restrict__ b1, const float* __restrict__ gb1,
    const float* __restrict__ b2, const float* __restrict__ gb2,
    const int* __restrict__ scene,
    ushort* __restrict__ sT0, ushort* __restrict__ sT1, ushort* __restrict__ sT2,
    float* __restrict__ bias0, float* __restrict__ bias1, float* __restrict__ bias2,
    int* __restrict__ bcnt, int* __restrict__ rank) {
  int bid = blockIdx.x, tid = threadIdx.x;
  if (bid < NB_W0) {
    int l = bid;
    st_tile(W0, gW0, sT0, 512, 512, l / 256, (l % 16) * 32, ((l / 16) % 16) * 32, tid);
  } else if (bid < NB_W0 + NB_W1) {
    int l = bid - NB_W0;
    st_tile(W1, gW1, sT1, 512, 256, l / 128, (l % 8) * 32, ((l / 8) % 16) * 32, tid);
  } else if (bid < NB_W0 + NB_W1 + NB_W2) {
    int l = bid - NB_W0 - NB_W1;
    st_tile(W2, gW2, sT2, 256, 64, l / 16, (l % 2) * 32, ((l / 2) % 8) * 32, tid);
  } else if (bid < NB_W0 + NB_W1 + NB_W2 + NB_BIAS) {
    int t = (bid - NB_W0 - NB_W1 - NB_W2) * 256 + tid;
    if (t < 7 * 512) bias0[t] = b0[t] + gb0[t & 511];
    else if (t < 7 * 512 + 7 * 256) { int i = t - 7 * 512; bias1[i] = b1[i] + gb1[i & 255]; }
    else if (t < 7 * 512 + 7 * 256 + 7 * 64) { int i = t - 7 * 512 - 7 * 256; bias2[i] = b2[i] + gb2[i & 63]; }
  } else {
    __shared__ int l[NSCENE];
    if (tid < NSCENE) l[tid] = 0;
    __syncthreads();
    int blk = bid - NB_W0 - NB_W1 - NB_W2 - NB_BIAS;
    int i = blk * 256 + tid;
    int pos = atomicAdd(&l[scene[i] - 1], 1);   // LDS atomic: rank in block
    rank[i] = pos;
    __syncthreads();
    if (tid < NSCENE) bcnt[blk * NSCENE + tid] = l[tid];
  }
}

// meta: [16..23]=padoff [24]=ntiles [32..191]=tile_scene [192..351]=tile_row
__global__ void plan_k(const int* __restrict__ bcnt, int* __restrict__ meta,
                       int* __restrict__ bbase, int* __restrict__ idxp) {
  __shared__ int tot[NSCENE], pstart[NSCENE], pend[NSCENE];
  int tid = threadIdx.x;
  if (tid < NSCENE) {
    int c = 0;
    for (int b = 0; b < NBLK; b++) c += bcnt[b * NSCENE + tid];
    tot[tid] = c;
  }
  __syncthreads();
  if (tid == 0) {
    int po = 0, t = 0;
    for (int s = 0; s < NSCENE; s++) {
      meta[16 + s] = po;
      int tiles = (tot[s] + TM - 1) / TM;
      pstart[s] = po + tot[s];
      pend[s] = po + tiles * TM;
      for (int j = 0; j < tiles; j++) { meta[32 + t] = s; meta[192 + t] = po + j * TM; t++; }
      po += tiles * TM;
    }
    meta[24] = t;
  }
  __syncthreads();
  if (tid < NSCENE) {
    int run = meta[16 + tid];
    for (int b = 0; b < NBLK; b++) { bbase[b * NSCENE + tid] = run; run += bcnt[b * NSCENE + tid]; }
  }
  for (int s = 0; s < NSCENE; s++)
    for (int i = pstart[s] + tid; i < pend[s]; i += 256) idxp[i] = -1;
}

// ---- xc: compact + fp32->bf16 convert x, write idxp ----------------------
// 2048 blocks x 256 thr; 32 threads/row, 16 elem (64B) per thread.
__global__ __launch_bounds__(256) void xc_k(const float* __restrict__ x,
                                            const int* __restrict__ scene,
                                            const int* __restrict__ rank,
                                            const int* __restrict__ bbase,
                                            int* __restrict__ idxp,
                                            ushort* __restrict__ xc) {
  int r = blockIdx.x * 8 + (threadIdx.x >> 5);
  int s = scene[r] - 1;
  int d = bbase[(r >> 8) * NSCENE + s] + rank[r];
  if ((threadIdx.x & 31) == 0) idxp[d] = r;
  int c = (threadIdx.x & 31) * 16;
  const float4* p = (const float4*)(x + (size_t)r * 512 + c);
  float4 f0 = p[0], f1 = p[1], f2 = p[2], f3 = p[3];
  uint4 v0, v1;
  v0.x = pk2(f0.x, f0.y); v0.y = pk2(f0.z, f0.w);
  v0.z = pk2(f1.x, f1.y); v0.w = pk2(f1.z, f1.w);
  v1.x = pk2(f2.x, f2.y); v1.y = pk2(f2.z, f2.w);
  v1.z = pk2(f3.x, f3.y); v1.w = pk2(f3.z, f3.w);
  uint4* q = (uint4*)(xc + (size_t)d * 512 + c);
  q[0] = v0; q[1] = v1;
}

// ---- L0 GEMM: hc1 = relu(xc @ sT0^T + bias0), TM=64 x TN=128 -------------
// 1080 blocks, 24KB LDS -> ~4 blk/CU of DMA/MFMA overlap (R9). XOR-swizzled
// LDS (16B chunks): chunk c=row*8+q holds global kchunk q^(row&7).
__global__ __launch_bounds__(256) void gemm0_k(
    const ushort* __restrict__ ain, const ushort* __restrict__ bw,
    const float* __restrict__ bias, const int* __restrict__ meta,
    ushort* __restrict__ hout) {
  int j = blockIdx.x;
  int t = j >> 1;
  if (t >= meta[24]) return;
  int sc = meta[32 + t];
  int mrow0 = meta[192 + t] + (j & 1) * 64;
  int nb = blockIdx.y;

  __shared__ __align__(16) ushort Abuf[64 * 64];    // 8 KB
  __shared__ __align__(16) ushort Bbuf[128 * 64];   // 16 KB

  int tid = threadIdx.x;
  int lane = tid & 63, wid = tid >> 6;   // wave covers 32 cols, all 64 rows

  f32x4 acc[4][2];
#pragma unroll
  for (int mt = 0; mt < 4; mt++)
#pragma unroll
    for (int nt = 0; nt < 2; nt++) acc[mt][nt] = (f32x4){0.f, 0.f, 0.f, 0.f};

  const ushort* bwS = bw + ((size_t)sc * 512 + (size_t)nb * 128) * 512;

  for (int kb = 0; kb < 8; kb++) {
#pragma unroll
    for (int i = 0; i < 2; i++) {             // A tile (64 x 64): 512 chunks
      int c = tid + i * 256;
      int row = c >> 3, q = c & 7;
      int kg = q ^ (row & 7);
      async16(ain + (size_t)(mrow0 + row) * 512 + kb * 64 + kg * 8,
              &Abuf[(size_t)(i * 256 + wid * 64) * 8]);
    }
#pragma unroll
    for (int i = 0; i < 4; i++) {             // B tile (128 x 64): 1024 chunks
      int c = tid + i * 256;
      int row = c >> 3, q = c & 7;
      int kg = q ^ (row & 7);
      async16(bwS + (size_t)row * 512 + kb * 64 + kg * 8,
              &Bbuf[(size_t)(i * 256 + wid * 64) * 8]);
    }
    __syncthreads();
#pragma unroll
    for (int kk = 0; kk < 64; kk += 32) {
      bf16x8 af[4], bfr[2];
      int kc = (kk >> 3) + (lane >> 4);
#pragma unroll
      for (int mt = 0; mt < 4; mt++) {
        int row = mt * 16 + (lane & 15);
        af[mt] = *(const bf16x8*)(&Abuf[(row * 8 + (kc ^ (row & 7))) * 8]);
      }
#pragma unroll
      for (int nt = 0; nt < 2; nt++) {
        int row = wid * 32 + nt * 16 + (lane & 15);
        bfr[nt] = *(const bf16x8*)(&Bbuf[(row * 8 + (kc ^ (row & 7))) * 8]);
      }
#pragma unroll
      for (int mt = 0; mt < 4; mt++)
#pragma unroll
        for (int nt = 0; nt < 2; nt++)
          acc[mt][nt] = __builtin_amdgcn_mfma_f32_16x16x32_bf16(af[mt], bfr[nt], acc[mt][nt], 0, 0, 0);
    }
    __syncthreads();
  }

  // epilogue: C/D layout col=lane&15, row=(lane>>4)*4+reg [m89-verified]
#pragma unroll
  for (int mt = 0; mt < 4; mt++) {
    int rl0 = mt * 16 + (lane >> 4) * 4;
#pragma unroll
    for (int nt = 0; nt < 2; nt++) {
      int col = nb * 128 + wid * 32 + nt * 16 + (lane & 15);
      float bv = bias[sc * 512 + col];
#pragma unroll
      for (int r = 0; r < 4; r++) {
        float v = fmaxf(acc[mt][nt][r] + bv, 0.f);
        hout[(size_t)(mrow0 + rl0 + r) * 512 + col] = f2bf(v);
      }
    }
  }
}

// ---- fused L1+L2, TM=64: h2 = relu(hc1 @ sT1^T + b1) in LDS;
//      out = h2 @ sT2^T + b2. 256 thr (4 waves), phase-1 BK=32, 52 KB LDS
//      -> 3 blocks/CU (R10).
__global__ __launch_bounds__(256) void gemm12_k(
    const ushort* __restrict__ hc1, const ushort* __restrict__ sT1,
    const ushort* __restrict__ sT2, const float* __restrict__ bias1,
    const float* __restrict__ bias2, const int* __restrict__ meta,
    const int* __restrict__ idxp, float* __restrict__ out) {
  int j = blockIdx.x;
  int t = j >> 1;
  if (t >= meta[24]) return;
  int sc = meta[32 + t];
  int mrow0 = meta[192 + t] + (j & 1) * 64;

  __shared__ __align__(16) ushort Abuf[64 * 32];    // 4 KB  (BK=32)
  __shared__ __align__(16) ushort Bbuf[256 * 32];   // 16 KB (BK=32; reused
                                                    //  as 64x256 in phase 2
                                                    //  -> see h2/Bbuf note)
  __shared__ __align__(16) ushort h2[64 * 256];     // 32 KB

  int tid = threadIdx.x;
  int lane = tid & 63, wid = tid >> 6;   // wave n-index

  // ---- phase 1: L1 (64 x 256, K=512), BK=32 slabs, wave tile 64x64 ----
  // Swizzle (4 chunks/row): LDS chunk c=row*4+q holds global kchunk
  // q^(row&3); staging linear-in-lane -> global_load_lds.
  f32x4 acc[4][4];
#pragma unroll
  for (int mt = 0; mt < 4; mt++)
#pragma unroll
    for (int nt = 0; nt < 4; nt++) acc[mt][nt] = (f32x4){0.f, 0.f, 0.f, 0.f};

  const ushort* b1p = sT1 + (size_t)sc * 256 * 512;

  for (int kb = 0; kb < 16; kb++) {
    {                                         // A tile (64 x 32): 256 chunks
      int c = tid;
      int row = c >> 2, q = c & 3;
      int kg = q ^ (row & 3);
      async16(hc1 + (size_t)(mrow0 + row) * 512 + kb * 32 + kg * 8,
              &Abuf[(size_t)(wid * 64) * 8]);
    }
#pragma unroll
    for (int i = 0; i < 4; i++) {             // B tile (256 x 32): 1024 chunks
      int c = tid + i * 256;
      int row = c >> 2, q = c & 3;
      int kg = q ^ (row & 3);
      async16(b1p + (size_t)row * 512 + kb * 32 + kg * 8,
              &Bbuf[(size_t)(i * 256 + wid * 64) * 8]);
    }
    __syncthreads();
    {
      bf16x8 af[4], bfr[4];
      int kc = lane >> 4;                     // 0..3
#pragma unroll
      for (int mt = 0; mt < 4; mt++) {
        int row = mt * 16 + (lane & 15);
        af[mt] = *(const bf16x8*)(&Abuf[(row * 4 + (kc ^ (row & 3))) * 8]);
      }
#pragma unroll
      for (int nt = 0; nt < 4; nt++) {
        int row = wid * 64 + nt * 16 + (lane & 15);
        bfr[nt] = *(const bf16x8*)(&Bbuf[(row * 4 + (kc ^ (row & 3))) * 8]);
      }
#pragma unroll
      for (int mt = 0; mt < 4; mt++)
#pragma unroll
        for (int nt = 0; nt < 4; nt++)
          acc[mt][nt] = __builtin_amdgcn_mfma_f32_16x16x32_bf16(af[mt], bfr[nt], acc[mt][nt], 0, 0, 0);
    }
    __syncthreads();
  }

  // epilogue 1 -> h2 LDS, XOR-swizzled 16B chunks: pos = row*32 + (kc^(row&7))
#pragma unroll
  for (int mt = 0; mt < 4; mt++) {
#pragma unroll
    for (int nt = 0; nt < 4; nt++) {
      int col = wid * 64 + nt * 16 + (lane & 15);
      float bv = bias1[sc * 256 + col];
#pragma unroll
      for (int r = 0; r < 4; r++) {
        int row = mt * 16 + (lane >> 4) * 4 + r;
        float v = fmaxf(acc[mt][nt][r] + bv, 0.f);
        h2[(row * 32 + ((col >> 3) ^ (row & 7))) * 8 + (col & 7)] = f2bf(v);
      }
    }
  }

  // ---- phase 2: L2 (64 x 64, K=256); stage sT2 slice (32 KB) into
  //      Bbuf(16K)+Abuf(4K)... doesn't fit -> stage in 2 halves of 16 KB.
  //      Half h covers output cols [h*32, h*32+32): rows 32, full K=256.
  const ushort* b2p = sT2 + (size_t)sc * 64 * 256;

  f32x4 acc2[4];
#pragma unroll
  for (int nt = 0; nt < 4; nt++) acc2[nt] = (f32x4){0.f, 0.f, 0.f, 0.f};

#pragma unroll
  for (int h = 0; h < 2; h++) {
#pragma unroll
    for (int i = 0; i < 4; i++) {             // 32 rows x 32 chunks = 1024
      int p = tid + i * 256;
      int row = p >> 5, pc = p & 31;
      int kg = pc ^ (row & 7);
      async16(b2p + (size_t)(h * 32 + row) * 256 + kg * 8,
              &Bbuf[(size_t)(i * 256 + wid * 64) * 8]);
    }
    __syncthreads();
#pragma unroll
    for (int kk = 0; kk < 256; kk += 32) {
      int kf = (kk >> 3) + (lane >> 4);
      bf16x8 af;
      {
        int row = wid * 16 + (lane & 15);     // wave owns 16 output rows
        af = *(const bf16x8*)(&h2[(row * 32 + (kf ^ (row & 7))) * 8]);
      }
      bf16x8 bfr[2];
#pragma unroll
      for (int nt = 0; nt < 2; nt++) {
        int n = nt * 16 + (lane & 15);        // local row in this half
        bfr[nt] = *(const bf16x8*)(&Bbuf[(n * 32 + (kf ^ (n & 7))) * 8]);
      }
#pragma unroll
      for (int nt = 0; nt < 2; nt++)
        acc2[h * 2 + nt] = __builtin_amdgcn_mfma_f32_16x16x32_bf16(af, bfr[nt], acc2[h * 2 + nt], 0, 0, 0);
    }
    __syncthreads();
  }

  // epilogue 2: scatter fp32 rows via idxp (pads have idxp<0)
  int gidx[4];
#pragma unroll
  for (int r = 0; r < 4; r++)
    gidx[r] = idxp[mrow0 + wid * 16 + (lane >> 4) * 4 + r];
#pragma unroll
  for (int nt = 0; nt < 4; nt++) {
    int col = nt * 16 + (lane & 15);          // acc2[h*2+j] -> cols h*32+j*16
    float bv = bias2[sc * 64 + col];
#pragma unroll
    for (int r = 0; r < 4; r++) {
      int g = gidx[r];
      if (g >= 0) out[(size_t)g * 64 + col] = acc2[nt][r] + bv;
    }
  }
}

extern "C" void kernel_launch(void* const* d_in, const int* in_sizes, int n_in,
                              void* d_out, int out_size, void* d_ws, size_t ws_size,
                              hipStream_t stream) {
  const float* x   = (const float*)d_in[0];
  const int* scene = (const int*)d_in[1];
  const float* W0  = (const float*)d_in[2];
  const float* b0  = (const float*)d_in[3];
  const float* gW0 = (const float*)d_in[4];
  const float* gb0 = (const float*)d_in[5];
  const float* W1  = (const float*)d_in[6];
  const float* b1  = (const float*)d_in[7];
  const float* gW1 = (const float*)d_in[8];
  const float* gb1 = (const float*)d_in[9];
  const float* W2  = (const float*)d_in[10];
  const float* b2  = (const float*)d_in[11];
  const float* gW2 = (const float*)d_in[12];
  const float* gb2 = (const float*)d_in[13];
  float* out = (float*)d_out;

  char* ws = (char*)d_ws;
  size_t off = 0;
  auto alloc = [&](size_t bytes) -> void* {
    void* p = ws + off;
    off = (off + bytes + 255) & ~(size_t)255;
    return p;
  };
  ushort* sT0   = (ushort*)alloc((size_t)7 * 512 * 512 * 2);
  ushort* sT1   = (ushort*)alloc((size_t)7 * 256 * 512 * 2);
  ushort* sT2   = (ushort*)alloc((size_t)7 * 64 * 256 * 2);
  float*  bias0 = (float*)alloc(7 * 512 * 4);
  float*  bias1 = (float*)alloc(7 * 256 * 4);
  float*  bias2 = (float*)alloc(7 * 64 * 4);
  int*    meta  = (int*)alloc(1024 * 4);
  int*    bcnt  = (int*)alloc(NBLK * NSCENE * 4);
  int*    bbase = (int*)alloc(NBLK * NSCENE * 4);
  int*    rank  = (int*)alloc(BATCH * 4);
  int*    idxp  = (int*)alloc(PADMAX * 4);
  ushort* xc    = (ushort*)alloc((size_t)PADMAX * 512 * 2);
  ushort* hc1   = (ushort*)alloc((size_t)PADMAX * 512 * 2);
  (void)ws_size; (void)n_in; (void)in_sizes; (void)out_size;

  prep_k<<<NB_W0 + NB_W1 + NB_W2 + NB_BIAS + NB_CNT, 256, 0, stream>>>(
      W0, gW0, W1, gW1, W2, gW2, b0, gb0, b1, gb1, b2, gb2, scene,
      sT0, sT1, sT2, bias0, bias1, bias2, bcnt, rank);
  plan_k<<<1, 256, 0, stream>>>(bcnt, meta, bbase, idxp);
  xc_k<<<BATCH / 8, 256, 0, stream>>>(x, scene, rank, bbase, idxp, xc);

  gemm0_k<<<dim3(MT_MAX * 2, 4), 256, 0, stream>>>(xc, sT0, bias0, meta, hc1);
  gemm12_k<<<dim3(MT_MAX * 2), 256, 0, stream>>>(hc1, sT1, sT2, bias1, bias2,
                                                 meta, idxp, out);
}

// Round 11
// 156.184 us; speedup vs baseline: 1.0171x; 1.0171x over previous
//
#include <hip/hip_runtime.h>
#include <hip/hip_bf16.h>
#include <stdint.h>

// STAR-DNN: per-sample scene-selected 3-layer MLP.
// R1: LDS-histogram compaction. R2: global_load_lds DMA. R4 (failed): grid
// barrier ~140us on 8 XCDs. R6 (failed): 135-blk fusion starved CUs.
// R8 (failed): gemm0 at 1 blk/CU latency-bound. R9: gemm0 TM=64/TN=128
// grid(270,4) ~4 blk/CU -> 155.8us (best). R10 (failed): gemm12 BK=32
// doubled barrier count, net -3us. R11: exact revert to R9.

#define BATCH   16384
#define NSCENE  7
#define TM      128
#define NBLK    (BATCH / 256)            // 64 count blocks
#define MT_MAX  (BATCH / TM + NSCENE)    // 135 worst-case tiles
#define PADMAX  (BATCH + NSCENE * TM)    // 17280 padded rows max

typedef __bf16 bf16x8 __attribute__((ext_vector_type(8)));
typedef float  f32x4  __attribute__((ext_vector_type(4)));

__device__ __forceinline__ ushort f2bf(float f) {
  union { float f; uint32_t u; } v; v.f = f;
  uint32_t r = (v.u + 0x7FFFu + ((v.u >> 16) & 1u)) >> 16;  // RNE
  return (ushort)r;
}
__device__ __forceinline__ uint32_t pk2(float a, float b) {
  union { __hip_bfloat162 h; uint32_t u; } cv;
  cv.h = __float22bfloat162_rn(make_float2(a, b));   // v_cvt_pk_bf16_f32
  return cv.u;
}
__device__ __forceinline__ void async16(const void* g, void* lds) {
  __builtin_amdgcn_global_load_lds(
      (const __attribute__((address_space(1))) uint32_t*)g,
      (__attribute__((address_space(3))) uint32_t*)lds, 16, 0, 0);
}

// ---- fused prep: W scale+transpose (x3), bias fuse, count+rank -----------
__device__ __forceinline__ void st_tile(const float* __restrict__ W,
                                        const float* __restrict__ gW,
                                        ushort* __restrict__ sT,
                                        int K, int N, int s, int n0, int k0,
                                        int tid) {
  __shared__ float tl[32][33];
  int tx = tid & 31, ty = tid >> 5;
  const float* Wp = W + (size_t)s * K * N;
#pragma unroll
  for (int i = 0; i < 4; i++) {
    int k = k0 + ty + i * 8;
    tl[ty + i * 8][tx] = Wp[(size_t)k * N + n0 + tx] * gW[(size_t)k * N + n0 + tx];
  }
  __syncthreads();
#pragma unroll
  for (int i = 0; i < 4; i++) {
    int n = n0 + ty + i * 8;
    sT[((size_t)s * N + n) * K + k0 + tx] = f2bf(tl[tx][ty + i * 8]);
  }
}

#define NB_W0 (16 * 16 * 7)
#define NB_W1 (8 * 16 * 7)
#define NB_W2 (2 * 8 * 7)
#define NB_BIAS 23
#define NB_CNT NBLK

__global__ __launch_bounds__(256) void prep_k(
    const float* __restrict__ W0, const float* __restrict__ gW0,
    const float* __restrict__ W1, const float* __restrict__ gW1,
    const float* __restrict__ W2, const float* __restrict__ gW2,
    const float* __restrict__ b0, const float* __restrict__ gb0,
    const float* __restrict__ b1, const float* __restrict__ gb1,
    const float* __restrict__ b2, const float* __restrict__ gb2,
    const int* __restrict__ scene,
    ushort* __restrict__ sT0, ushort* __restrict__ sT1, ushort* __restrict__ sT2,
    float* __restrict__ bias0, float* __restrict__ bias1, float* __restrict__ bias2,
    int* __restrict__ bcnt, int* __restrict__ rank) {
  int bid = blockIdx.x, tid = threadIdx.x;
  if (bid < NB_W0) {
    int l = bid;
    st_tile(W0, gW0, sT0, 512, 512, l / 256, (l % 16) * 32, ((l / 16) % 16) * 32, tid);
  } else if (bid < NB_W0 + NB_W1) {
    int l = bid - NB_W0;
    st_tile(W1, gW1, sT1, 512, 256, l / 128, (l % 8) * 32, ((l / 8) % 16) * 32, tid);
  } else if (bid < NB_W0 + NB_W1 + NB_W2) {
    int l = bid - NB_W0 - NB_W1;
    st_tile(W2, gW2, sT2, 256, 64, l / 16, (l % 2) * 32, ((l / 2) % 8) * 32, tid);
  } else if (bid < NB_W0 + NB_W1 + NB_W2 + NB_BIAS) {
    int t = (bid - NB_W0 - NB_W1 - NB_W2) * 256 + tid;
    if (t < 7 * 512) bias0[t] = b0[t] + gb0[t & 511];
    else if (t < 7 * 512 + 7 * 256) { int i = t - 7 * 512; bias1[i] = b1[i] + gb1[i & 255]; }
    else if (t < 7 * 512 + 7 * 256 + 7 * 64) { int i = t - 7 * 512 - 7 * 256; bias2[i] = b2[i] + gb2[i & 63]; }
  } else {
    __shared__ int l[NSCENE];
    if (tid < NSCENE) l[tid] = 0;
    __syncthreads();
    int blk = bid - NB_W0 - NB_W1 - NB_W2 - NB_BIAS;
    int i = blk * 256 + tid;
    int pos = atomicAdd(&l[scene[i] - 1], 1);   // LDS atomic: rank in block
    rank[i] = pos;
    __syncthreads();
    if (tid < NSCENE) bcnt[blk * NSCENE + tid] = l[tid];
  }
}

// meta: [16..23]=padoff [24]=ntiles [32..191]=tile_scene [192..351]=tile_row
__global__ void plan_k(const int* __restrict__ bcnt, int* __restrict__ meta,
                       int* __restrict__ bbase, int* __restrict__ idxp) {
  __shared__ int tot[NSCENE], pstart[NSCENE], pend[NSCENE];
  int tid = threadIdx.x;
  if (tid < NSCENE) {
    int c = 0;
    for (int b = 0; b < NBLK; b++) c += bcnt[b * NSCENE + tid];
    tot[tid] = c;
  }
  __syncthreads();
  if (tid == 0) {
    int po = 0, t = 0;
    for (int s = 0; s < NSCENE; s++) {
      meta[16 + s] = po;
      int tiles = (tot[s] + TM - 1) / TM;
      pstart[s] = po + tot[s];
      pend[s] = po + tiles * TM;
      for (int j = 0; j < tiles; j++) { meta[32 + t] = s; meta[192 + t] = po + j * TM; t++; }
      po += tiles * TM;
    }
    meta[24] = t;
  }
  __syncthreads();
  if (tid < NSCENE) {
    int run = meta[16 + tid];
    for (int b = 0; b < NBLK; b++) { bbase[b * NSCENE + tid] = run; run += bcnt[b * NSCENE + tid]; }
  }
  for (int s = 0; s < NSCENE; s++)
    for (int i = pstart[s] + tid; i < pend[s]; i += 256) idxp[i] = -1;
}

// ---- xc: compact + fp32->bf16 convert x, write idxp ----------------------
// 2048 blocks x 256 thr; 32 threads/row, 16 elem (64B) per thread.
__global__ __launch_bounds__(256) void xc_k(const float* __restrict__ x,
                                            const int* __restrict__ scene,
                                            const int* __restrict__ rank,
                                            const int* __restrict__ bbase,
                                            int* __restrict__ idxp,
                                            ushort* __restrict__ xc) {
  int r = blockIdx.x * 8 + (threadIdx.x >> 5);
  int s = scene[r] - 1;
  int d = bbase[(r >> 8) * NSCENE + s] + rank[r];
  if ((threadIdx.x & 31) == 0) idxp[d] = r;
  int c = (threadIdx.x & 31) * 16;
  const float4* p = (const float4*)(x + (size_t)r * 512 + c);
  float4 f0 = p[0], f1 = p[1], f2 = p[2], f3 = p[3];
  uint4 v0, v1;
  v0.x = pk2(f0.x, f0.y); v0.y = pk2(f0.z, f0.w);
  v0.z = pk2(f1.x, f1.y); v0.w = pk2(f1.z, f1.w);
  v1.x = pk2(f2.x, f2.y); v1.y = pk2(f2.z, f2.w);
  v1.z = pk2(f3.x, f3.y); v1.w = pk2(f3.z, f3.w);
  uint4* q = (uint4*)(xc + (size_t)d * 512 + c);
  q[0] = v0; q[1] = v1;
}

// ---- L0 GEMM: hc1 = relu(xc @ sT0^T + bias0), TM=64 x TN=128 -------------
// 1080 blocks, 24KB LDS -> ~4 blk/CU of DMA/MFMA overlap (R9). XOR-swizzled
// LDS (16B chunks): chunk c=row*8+q holds global kchunk q^(row&7).
__global__ __launch_bounds__(256) void gemm0_k(
    const ushort* __restrict__ ain, const ushort* __restrict__ bw,
    const float* __restrict__ bias, const int* __restrict__ meta,
    ushort* __restrict__ hout) {
  int j = blockIdx.x;
  int t = j >> 1;
  if (t >= meta[24]) return;
  int sc = meta[32 + t];
  int mrow0 = meta[192 + t] + (j & 1) * 64;
  int nb = blockIdx.y;

  __shared__ __align__(16) ushort Abuf[64 * 64];    // 8 KB
  __shared__ __align__(16) ushort Bbuf[128 * 64];   // 16 KB

  int tid = threadIdx.x;
  int lane = tid & 63, wid = tid >> 6;   // wave covers 32 cols, all 64 rows

  f32x4 acc[4][2];
#pragma unroll
  for (int mt = 0; mt < 4; mt++)
#pragma unroll
    for (int nt = 0; nt < 2; nt++) acc[mt][nt] = (f32x4){0.f, 0.f, 0.f, 0.f};

  const ushort* bwS = bw + ((size_t)sc * 512 + (size_t)nb * 128) * 512;

  for (int kb = 0; kb < 8; kb++) {
#pragma unroll
    for (int i = 0; i < 2; i++) {             // A tile (64 x 64): 512 chunks
      int c = tid + i * 256;
      int row = c >> 3, q = c & 7;
      int kg = q ^ (row & 7);
      async16(ain + (size_t)(mrow0 + row) * 512 + kb * 64 + kg * 8,
              &Abuf[(size_t)(i * 256 + wid * 64) * 8]);
    }
#pragma unroll
    for (int i = 0; i < 4; i++) {             // B tile (128 x 64): 1024 chunks
      int c = tid + i * 256;
      int row = c >> 3, q = c & 7;
      int kg = q ^ (row & 7);
      async16(bwS + (size_t)row * 512 + kb * 64 + kg * 8,
              &Bbuf[(size_t)(i * 256 + wid * 64) * 8]);
    }
    __syncthreads();
#pragma unroll
    for (int kk = 0; kk < 64; kk += 32) {
      bf16x8 af[4], bfr[2];
      int kc = (kk >> 3) + (lane >> 4);
#pragma unroll
      for (int mt = 0; mt < 4; mt++) {
        int row = mt * 16 + (lane & 15);
        af[mt] = *(const bf16x8*)(&Abuf[(row * 8 + (kc ^ (row & 7))) * 8]);
      }
#pragma unroll
      for (int nt = 0; nt < 2; nt++) {
        int row = wid * 32 + nt * 16 + (lane & 15);
        bfr[nt] = *(const bf16x8*)(&Bbuf[(row * 8 + (kc ^ (row & 7))) * 8]);
      }
#pragma unroll
      for (int mt = 0; mt < 4; mt++)
#pragma unroll
        for (int nt = 0; nt < 2; nt++)
          acc[mt][nt] = __builtin_amdgcn_mfma_f32_16x16x32_bf16(af[mt], bfr[nt], acc[mt][nt], 0, 0, 0);
    }
    __syncthreads();
  }

  // epilogue: C/D layout col=lane&15, row=(lane>>4)*4+reg [m89-verified]
#pragma unroll
  for (int mt = 0; mt < 4; mt++) {
    int rl0 = mt * 16 + (lane >> 4) * 4;
#pragma unroll
    for (int nt = 0; nt < 2; nt++) {
      int col = nb * 128 + wid * 32 + nt * 16 + (lane & 15);
      float bv = bias[sc * 512 + col];
#pragma unroll
      for (int r = 0; r < 4; r++) {
        float v = fmaxf(acc[mt][nt][r] + bv, 0.f);
        hout[(size_t)(mrow0 + rl0 + r) * 512 + col] = f2bf(v);
      }
    }
  }
}

// ---- fused L1+L2, TM=64: h2 = relu(hc1 @ sT1^T + b1) in LDS;
//      out = h2 @ sT2^T + b2. 256 thr (4 waves), BK=64, 72 KB LDS (R9).
__global__ __launch_bounds__(256) void gemm12_k(
    const ushort* __restrict__ hc1, const ushort* __restrict__ sT1,
    const ushort* __restrict__ sT2, const float* __restrict__ bias1,
    const float* __restrict__ bias2, const int* __restrict__ meta,
    const int* __restrict__ idxp, float* __restrict__ out) {
  int j = blockIdx.x;
  int t = j >> 1;
  if (t >= meta[24]) return;
  int sc = meta[32 + t];
  int mrow0 = meta[192 + t] + (j & 1) * 64;

  __shared__ __align__(16) ushort Abuf[64 * 64];    // 8 KB
  __shared__ __align__(16) ushort Bbuf[256 * 64];   // 32 KB
  __shared__ __align__(16) ushort h2[64 * 256];     // 32 KB

  int tid = threadIdx.x;
  int lane = tid & 63, wid = tid >> 6;   // wave n-index

  // ---- phase 1: L1 (64 x 256, K=512), wave tile 64x64 ----
  f32x4 acc[4][4];
#pragma unroll
  for (int mt = 0; mt < 4; mt++)
#pragma unroll
    for (int nt = 0; nt < 4; nt++) acc[mt][nt] = (f32x4){0.f, 0.f, 0.f, 0.f};

  const ushort* b1p = sT1 + (size_t)sc * 256 * 512;

  for (int kb = 0; kb < 8; kb++) {
#pragma unroll
    for (int i = 0; i < 2; i++) {             // A tile (64 x 64): 512 chunks
      int c = tid + i * 256;
      int row = c >> 3, q = c & 7;
      int kg = q ^ (row & 7);
      async16(hc1 + (size_t)(mrow0 + row) * 512 + kb * 64 + kg * 8,
              &Abuf[(size_t)(i * 256 + wid * 64) * 8]);
    }
#pragma unroll
    for (int i = 0; i < 8; i++) {             // B tile (256 x 64): 2048 chunks
      int c = tid + i * 256;
      int row = c >> 3, q = c & 7;
      int kg = q ^ (row & 7);
      async16(b1p + (size_t)row * 512 + kb * 64 + kg * 8,
              &Bbuf[(size_t)(i * 256 + wid * 64) * 8]);
    }
    __syncthreads();
#pragma unroll
    for (int kk = 0; kk < 64; kk += 32) {
      bf16x8 af[4], bfr[4];
      int kc = (kk >> 3) + (lane >> 4);
#pragma unroll
      for (int mt = 0; mt < 4; mt++) {
        int row = mt * 16 + (lane & 15);
        af[mt] = *(const bf16x8*)(&Abuf[(row * 8 + (kc ^ (row & 7))) * 8]);
      }
#pragma unroll
      for (int nt = 0; nt < 4; nt++) {
        int row = wid * 64 + nt * 16 + (lane & 15);
        bfr[nt] = *(const bf16x8*)(&Bbuf[(row * 8 + (kc ^ (row & 7))) * 8]);
      }
#pragma unroll
      for (int mt = 0; mt < 4; mt++)
#pragma unroll
        for (int nt = 0; nt < 4; nt++)
          acc[mt][nt] = __builtin_amdgcn_mfma_f32_16x16x32_bf16(af[mt], bfr[nt], acc[mt][nt], 0, 0, 0);
    }
    __syncthreads();
  }

  // epilogue 1 -> h2 LDS, XOR-swizzled 16B chunks: pos = row*32 + (kc^(row&7))
#pragma unroll
  for (int mt = 0; mt < 4; mt++) {
#pragma unroll
    for (int nt = 0; nt < 4; nt++) {
      int col = wid * 64 + nt * 16 + (lane & 15);
      float bv = bias1[sc * 256 + col];
#pragma unroll
      for (int r = 0; r < 4; r++) {
        int row = mt * 16 + (lane >> 4) * 4 + r;
        float v = fmaxf(acc[mt][nt][r] + bv, 0.f);
        h2[(row * 32 + ((col >> 3) ^ (row & 7))) * 8 + (col & 7)] = f2bf(v);
      }
    }
  }

  // ---- phase 2: L2 (64 x 64, K=256); stage full sT2 slice (32 KB) once ----
  const ushort* b2p = sT2 + (size_t)sc * 64 * 256;
#pragma unroll
  for (int i = 0; i < 8; i++) {               // 64 rows x 32 chunks
    int p = tid + i * 256;
    int row = p >> 5, pc = p & 31;
    int kg = pc ^ (row & 7);
    async16(b2p + (size_t)row * 256 + kg * 8,
            &Bbuf[(size_t)(i * 256 + wid * 64) * 8]);
  }
  __syncthreads();

  f32x4 acc2[4];
#pragma unroll
  for (int nt = 0; nt < 4; nt++) acc2[nt] = (f32x4){0.f, 0.f, 0.f, 0.f};

#pragma unroll
  for (int kk = 0; kk < 256; kk += 32) {
    int kf = (kk >> 3) + (lane >> 4);
    bf16x8 af;
    {
      int row = wid * 16 + (lane & 15);       // wave owns 16 output rows
      af = *(const bf16x8*)(&h2[(row * 32 + (kf ^ (row & 7))) * 8]);
    }
    bf16x8 bfr[4];
#pragma unroll
    for (int nt = 0; nt < 4; nt++) {
      int n = nt * 16 + (lane & 15);
      bfr[nt] = *(const bf16x8*)(&Bbuf[(n * 32 + (kf ^ (n & 7))) * 8]);
    }
#pragma unroll
    for (int nt = 0; nt < 4; nt++)
      acc2[nt] = __builtin_amdgcn_mfma_f32_16x16x32_bf16(af, bfr[nt], acc2[nt], 0, 0, 0);
  }

  // epilogue 2: scatter fp32 rows via idxp (pads have idxp<0)
  int gidx[4];
#pragma unroll
  for (int r = 0; r < 4; r++)
    gidx[r] = idxp[mrow0 + wid * 16 + (lane >> 4) * 4 + r];
#pragma unroll
  for (int nt = 0; nt < 4; nt++) {
    int col = nt * 16 + (lane & 15);
    float bv = bias2[sc * 64 + col];
#pragma unroll
    for (int r = 0; r < 4; r++) {
      int g = gidx[r];
      if (g >= 0) out[(size_t)g * 64 + col] = acc2[nt][r] + bv;
    }
  }
}

extern "C" void kernel_launch(void* const* d_in, const int* in_sizes, int n_in,
                              void* d_out, int out_size, void* d_ws, size_t ws_size,
                              hipStream_t stream) {
  const float* x   = (const float*)d_in[0];
  const int* scene = (const int*)d_in[1];
  const float* W0  = (const float*)d_in[2];
  const float* b0  = (const float*)d_in[3];
  const float* gW0 = (const float*)d_in[4];
  const float* gb0 = (const float*)d_in[5];
  const float* W1  = (const float*)d_in[6];
  const float* b1  = (const float*)d_in[7];
  const float* gW1 = (const float*)d_in[8];
  const float* gb1 = (const float*)d_in[9];
  const float* W2  = (const float*)d_in[10];
  const float* b2  = (const float*)d_in[11];
  const float* gW2 = (const float*)d_in[12];
  const float* gb2 = (const float*)d_in[13];
  float* out = (float*)d_out;

  char* ws = (char*)d_ws;
  size_t off = 0;
  auto alloc = [&](size_t bytes) -> void* {
    void* p = ws + off;
    off = (off + bytes + 255) & ~(size_t)255;
    return p;
  };
  ushort* sT0   = (ushort*)alloc((size_t)7 * 512 * 512 * 2);
  ushort* sT1   = (ushort*)alloc((size_t)7 * 256 * 512 * 2);
  ushort* sT2   = (ushort*)alloc((size_t)7 * 64 * 256 * 2);
  float*  bias0 = (float*)alloc(7 * 512 * 4);
  float*  bias1 = (float*)alloc(7 * 256 * 4);
  float*  bias2 = (float*)alloc(7 * 64 * 4);
  int*    meta  = (int*)alloc(1024 * 4);
  int*    bcnt  = (int*)alloc(NBLK * NSCENE * 4);
  int*    bbase = (int*)alloc(NBLK * NSCENE * 4);
  int*    rank  = (int*)alloc(BATCH * 4);
  int*    idxp  = (int*)alloc(PADMAX * 4);
  ushort* xc    = (ushort*)alloc((size_t)PADMAX * 512 * 2);
  ushort* hc1   = (ushort*)alloc((size_t)PADMAX * 512 * 2);
  (void)ws_size; (void)n_in; (void)in_sizes; (void)out_size;

  prep_k<<<NB_W0 + NB_W1 + NB_W2 + NB_BIAS + NB_CNT, 256, 0, stream>>>(
      W0, gW0, W1, gW1, W2, gW2, b0, gb0, b1, gb1, b2, gb2, scene,
      sT0, sT1, sT2, bias0, bias1, bias2, bcnt, rank);
  plan_k<<<1, 256, 0, stream>>>(bcnt, meta, bbase, idxp);
  xc_k<<<BATCH / 8, 256, 0, stream>>>(x, scene, rank, bbase, idxp, xc);

  gemm0_k<<<dim3(MT_MAX * 2, 4), 256, 0, stream>>>(xc, sT0, bias0, meta, hc1);
  gemm12_k<<<dim3(MT_MAX * 2), 256, 0, stream>>>(hc1, sT1, sT2, bias1, bias2,
                                                 meta, idxp, out);
}

// Round 12
// 152.841 us; speedup vs baseline: 1.0394x; 1.0219x over previous
//
#include <hip/hip_runtime.h>
#include <hip/hip_bf16.h>
#include <stdint.h>

// STAR-DNN: per-sample scene-selected 3-layer MLP.
// R1: LDS-histogram compaction. R2: global_load_lds DMA. R4 (failed): grid
// barrier ~140us on 8 XCDs. R6 (failed): 135-blk fusion starved CUs.
// R8 (failed): gemm0 at 1 blk/CU latency-bound. R9/R11: gemm0 TM=64/TN=128
// grid(270,4), gemm12 BK=64 -> 155.8us best. R10 (failed): BK=32 doubled
// barriers. R12: plan_k removed -- every consumer derives the plan from
// bcnt (448 ints) per-block; idxp pad-fill replaced by tot-guard. 4 launches.

#define BATCH   16384
#define NSCENE  7
#define TM      128
#define NBLK    (BATCH / 256)            // 64 count blocks
#define MT_MAX  (BATCH / TM + NSCENE)    // 135 worst-case tiles
#define PADMAX  (BATCH + NSCENE * TM)    // 17280 padded rows max

typedef __bf16 bf16x8 __attribute__((ext_vector_type(8)));
typedef float  f32x4  __attribute__((ext_vector_type(4)));

__device__ __forceinline__ ushort f2bf(float f) {
  union { float f; uint32_t u; } v; v.f = f;
  uint32_t r = (v.u + 0x7FFFu + ((v.u >> 16) & 1u)) >> 16;  // RNE
  return (ushort)r;
}
__device__ __forceinline__ uint32_t pk2(float a, float b) {
  union { __hip_bfloat162 h; uint32_t u; } cv;
  cv.h = __float22bfloat162_rn(make_float2(a, b));   // v_cvt_pk_bf16_f32
  return cv.u;
}
__device__ __forceinline__ void async16(const void* g, void* lds) {
  __builtin_amdgcn_global_load_lds(
      (const __attribute__((address_space(1))) uint32_t*)g,
      (__attribute__((address_space(3))) uint32_t*)lds, 16, 0, 0);
}

// ---- fused prep: W scale+transpose (x3), bias fuse, count+rank -----------
__device__ __forceinline__ void st_tile(const float* __restrict__ W,
                                        const float* __restrict__ gW,
                                        ushort* __restrict__ sT,
                                        int K, int N, int s, int n0, int k0,
                                        int tid) {
  __shared__ float tl[32][33];
  int tx = tid & 31, ty = tid >> 5;
  const float* Wp = W + (size_t)s * K * N;
#pragma unroll
  for (int i = 0; i < 4; i++) {
    int k = k0 + ty + i * 8;
    tl[ty + i * 8][tx] = Wp[(size_t)k * N + n0 + tx] * gW[(size_t)k * N + n0 + tx];
  }
  __syncthreads();
#pragma unroll
  for (int i = 0; i < 4; i++) {
    int n = n0 + ty + i * 8;
    sT[((size_t)s * N + n) * K + k0 + tx] = f2bf(tl[tx][ty + i * 8]);
  }
}

#define NB_W0 (16 * 16 * 7)
#define NB_W1 (8 * 16 * 7)
#define NB_W2 (2 * 8 * 7)
#define NB_BIAS 23
#define NB_CNT NBLK

__global__ __launch_bounds__(256) void prep_k(
    const float* __restrict__ W0, const float* __restrict__ gW0,
    const float* __restrict__ W1, const float* __restrict__ gW1,
    const float* __restrict__ W2, const float* __restrict__ gW2,
    const float* __restrict__ b0, const float* __restrict__ gb0,
    const float* __restrict__ b1, const float* __restrict__ gb1,
    const float* __restrict__ b2, const float* __restrict__ gb2,
    const int* __restrict__ scene,
    ushort* __restrict__ sT0, ushort* __restrict__ sT1, ushort* __restrict__ sT2,
    float* __restrict__ bias0, float* __restrict__ bias1, float* __restrict__ bias2,
    int* __restrict__ bcnt, int* __restrict__ rank) {
  int bid = blockIdx.x, tid = threadIdx.x;
  if (bid < NB_W0) {
    int l = bid;
    st_tile(W0, gW0, sT0, 512, 512, l / 256, (l % 16) * 32, ((l / 16) % 16) * 32, tid);
  } else if (bid < NB_W0 + NB_W1) {
    int l = bid - NB_W0;
    st_tile(W1, gW1, sT1, 512, 256, l / 128, (l % 8) * 32, ((l / 8) % 16) * 32, tid);
  } else if (bid < NB_W0 + NB_W1 + NB_W2) {
    int l = bid - NB_W0 - NB_W1;
    st_tile(W2, gW2, sT2, 256, 64, l / 16, (l % 2) * 32, ((l / 2) % 8) * 32, tid);
  } else if (bid < NB_W0 + NB_W1 + NB_W2 + NB_BIAS) {
    int t = (bid - NB_W0 - NB_W1 - NB_W2) * 256 + tid;
    if (t < 7 * 512) bias0[t] = b0[t] + gb0[t & 511];
    else if (t < 7 * 512 + 7 * 256) { int i = t - 7 * 512; bias1[i] = b1[i] + gb1[i & 255]; }
    else if (t < 7 * 512 + 7 * 256 + 7 * 64) { int i = t - 7 * 512 - 7 * 256; bias2[i] = b2[i] + gb2[i & 63]; }
  } else {
    __shared__ int l[NSCENE];
    if (tid < NSCENE) l[tid] = 0;
    __syncthreads();
    int blk = bid - NB_W0 - NB_W1 - NB_W2 - NB_BIAS;
    int i = blk * 256 + tid;
    int pos = atomicAdd(&l[scene[i] - 1], 1);   // LDS atomic: rank in block
    rank[i] = pos;
    __syncthreads();
    if (tid < NSCENE) bcnt[blk * NSCENE + tid] = l[tid];
  }
}

// ---- per-block plan derivation from bcnt (replaces plan_k) ---------------
// sb[448] <- bcnt; tot[s]=sum_b; padoff[s]=cum padded rows; cumt[s]=cum tiles.
#define PLAN_SHARED  __shared__ int sb[NBLK * NSCENE]; \
                     __shared__ int tot[NSCENE], padoff[NSCENE], cumt[NSCENE + 1];
__device__ __forceinline__ void plan_derive(const int* __restrict__ bcnt,
                                            int* sb, int* tot, int* padoff,
                                            int* cumt, int tid) {
  if (tid < NBLK * NSCENE) sb[tid] = bcnt[tid];
  if (tid + 256 < NBLK * NSCENE) sb[tid + 256] = bcnt[tid + 256];
  __syncthreads();
  if (tid < NSCENE) {
    int c = 0;
    for (int b = 0; b < NBLK; b++) c += sb[b * NSCENE + tid];
    tot[tid] = c;
  }
  __syncthreads();
  if (tid == 0) {
    int po = 0, ct = 0;
    for (int s = 0; s < NSCENE; s++) {
      padoff[s] = po; cumt[s] = ct;
      int tiles = (tot[s] + TM - 1) / TM;
      ct += tiles; po += tiles * TM;
    }
    cumt[NSCENE] = ct;
  }
  __syncthreads();
}

// ---- xc: compact + fp32->bf16 convert x, write idxp ----------------------
// 2048 blocks x 256 thr; 32 threads/row, 16 elem (64B) per thread.
__global__ __launch_bounds__(256) void xc_k(const float* __restrict__ x,
                                            const int* __restrict__ scene,
                                            const int* __restrict__ rank,
                                            const int* __restrict__ bcnt,
                                            int* __restrict__ idxp,
                                            ushort* __restrict__ xc) {
  PLAN_SHARED
  __shared__ int base7[NSCENE];
  int tid = threadIdx.x;
  plan_derive(bcnt, sb, tot, padoff, cumt, tid);
  int myblk = blockIdx.x >> 5;      // this block's 8 rows share a count-block
  if (tid < NSCENE) {
    int pre = 0;
    for (int b = 0; b < myblk; b++) pre += sb[b * NSCENE + tid];
    base7[tid] = padoff[tid] + pre;
  }
  __syncthreads();

  int r = blockIdx.x * 8 + (tid >> 5);
  int s = scene[r] - 1;
  int d = base7[s] + rank[r];
  if ((tid & 31) == 0) idxp[d] = r;
  int c = (tid & 31) * 16;
  const float4* p = (const float4*)(x + (size_t)r * 512 + c);
  float4 f0 = p[0], f1 = p[1], f2 = p[2], f3 = p[3];
  uint4 v0, v1;
  v0.x = pk2(f0.x, f0.y); v0.y = pk2(f0.z, f0.w);
  v0.z = pk2(f1.x, f1.y); v0.w = pk2(f1.z, f1.w);
  v1.x = pk2(f2.x, f2.y); v1.y = pk2(f2.z, f2.w);
  v1.z = pk2(f3.x, f3.y); v1.w = pk2(f3.z, f3.w);
  uint4* q = (uint4*)(xc + (size_t)d * 512 + c);
  q[0] = v0; q[1] = v1;
}

// ---- L0 GEMM: hc1 = relu(xc @ sT0^T + bias0), TM=64 x TN=128 -------------
// 1080 blocks, ~26KB LDS -> ~4 blk/CU of DMA/MFMA overlap (R9). XOR-swizzled
// LDS (16B chunks): chunk c=row*8+q holds global kchunk q^(row&7).
__global__ __launch_bounds__(256) void gemm0_k(
    const ushort* __restrict__ ain, const ushort* __restrict__ bw,
    const float* __restrict__ bias, const int* __restrict__ bcnt,
    ushort* __restrict__ hout) {
  PLAN_SHARED
  __shared__ __align__(16) ushort Abuf[64 * 64];    // 8 KB
  __shared__ __align__(16) ushort Bbuf[128 * 64];   // 16 KB

  int tid = threadIdx.x;
  plan_derive(bcnt, sb, tot, padoff, cumt, tid);

  int j = blockIdx.x;
  int t = j >> 1;
  if (t >= cumt[NSCENE]) return;
  int sc = 0;
  while (sc < NSCENE - 1 && t >= cumt[sc + 1]) sc++;
  int mrow0 = padoff[sc] + (t - cumt[sc]) * TM + (j & 1) * 64;
  int nb = blockIdx.y;

  int lane = tid & 63, wid = tid >> 6;   // wave covers 32 cols, all 64 rows

  f32x4 acc[4][2];
#pragma unroll
  for (int mt = 0; mt < 4; mt++)
#pragma unroll
    for (int nt = 0; nt < 2; nt++) acc[mt][nt] = (f32x4){0.f, 0.f, 0.f, 0.f};

  const ushort* bwS = bw + ((size_t)sc * 512 + (size_t)nb * 128) * 512;

  for (int kb = 0; kb < 8; kb++) {
#pragma unroll
    for (int i = 0; i < 2; i++) {             // A tile (64 x 64): 512 chunks
      int c = tid + i * 256;
      int row = c >> 3, q = c & 7;
      int kg = q ^ (row & 7);
      async16(ain + (size_t)(mrow0 + row) * 512 + kb * 64 + kg * 8,
              &Abuf[(size_t)(i * 256 + wid * 64) * 8]);
    }
#pragma unroll
    for (int i = 0; i < 4; i++) {             // B tile (128 x 64): 1024 chunks
      int c = tid + i * 256;
      int row = c >> 3, q = c & 7;
      int kg = q ^ (row & 7);
      async16(bwS + (size_t)row * 512 + kb * 64 + kg * 8,
              &Bbuf[(size_t)(i * 256 + wid * 64) * 8]);
    }
    __syncthreads();
#pragma unroll
    for (int kk = 0; kk < 64; kk += 32) {
      bf16x8 af[4], bfr[2];
      int kc = (kk >> 3) + (lane >> 4);
#pragma unroll
      for (int mt = 0; mt < 4; mt++) {
        int row = mt * 16 + (lane & 15);
        af[mt] = *(const bf16x8*)(&Abuf[(row * 8 + (kc ^ (row & 7))) * 8]);
      }
#pragma unroll
      for (int nt = 0; nt < 2; nt++) {
        int row = wid * 32 + nt * 16 + (lane & 15);
        bfr[nt] = *(const bf16x8*)(&Bbuf[(row * 8 + (kc ^ (row & 7))) * 8]);
      }
#pragma unroll
      for (int mt = 0; mt < 4; mt++)
#pragma unroll
        for (int nt = 0; nt < 2; nt++)
          acc[mt][nt] = __builtin_amdgcn_mfma_f32_16x16x32_bf16(af[mt], bfr[nt], acc[mt][nt], 0, 0, 0);
    }
    __syncthreads();
  }

  // epilogue: C/D layout col=lane&15, row=(lane>>4)*4+reg [m89-verified]
#pragma unroll
  for (int mt = 0; mt < 4; mt++) {
    int rl0 = mt * 16 + (lane >> 4) * 4;
#pragma unroll
    for (int nt = 0; nt < 2; nt++) {
      int col = nb * 128 + wid * 32 + nt * 16 + (lane & 15);
      float bv = bias[sc * 512 + col];
#pragma unroll
      for (int r = 0; r < 4; r++) {
        float v = fmaxf(acc[mt][nt][r] + bv, 0.f);
        hout[(size_t)(mrow0 + rl0 + r) * 512 + col] = f2bf(v);
      }
    }
  }
}

// ---- fused L1+L2, TM=64: h2 = relu(hc1 @ sT1^T + b1) in LDS;
//      out = h2 @ sT2^T + b2. 256 thr (4 waves), BK=64, ~74 KB LDS (R9).
__global__ __launch_bounds__(256) void gemm12_k(
    const ushort* __restrict__ hc1, const ushort* __restrict__ sT1,
    const ushort* __restrict__ sT2, const float* __restrict__ bias1,
    const float* __restrict__ bias2, const int* __restrict__ bcnt,
    const int* __restrict__ idxp, float* __restrict__ out) {
  PLAN_SHARED
  __shared__ __align__(16) ushort Abuf[64 * 64];    // 8 KB
  __shared__ __align__(16) ushort Bbuf[256 * 64];   // 32 KB
  __shared__ __align__(16) ushort h2[64 * 256];     // 32 KB

  int tid = threadIdx.x;
  plan_derive(bcnt, sb, tot, padoff, cumt, tid);

  int j = blockIdx.x;
  int t = j >> 1;
  if (t >= cumt[NSCENE]) return;
  int sc = 0;
  while (sc < NSCENE - 1 && t >= cumt[sc + 1]) sc++;
  int mrow0 = padoff[sc] + (t - cumt[sc]) * TM + (j & 1) * 64;
  int maxloc = padoff[sc] + tot[sc];   // rows >= maxloc are pads

  int lane = tid & 63, wid = tid >> 6;   // wave n-index

  // ---- phase 1: L1 (64 x 256, K=512), wave tile 64x64 ----
  f32x4 acc[4][4];
#pragma unroll
  for (int mt = 0; mt < 4; mt++)
#pragma unroll
    for (int nt = 0; nt < 4; nt++) acc[mt][nt] = (f32x4){0.f, 0.f, 0.f, 0.f};

  const ushort* b1p = sT1 + (size_t)sc * 256 * 512;

  for (int kb = 0; kb < 8; kb++) {
#pragma unroll
    for (int i = 0; i < 2; i++) {             // A tile (64 x 64): 512 chunks
      int c = tid + i * 256;
      int row = c >> 3, q = c & 7;
      int kg = q ^ (row & 7);
      async16(hc1 + (size_t)(mrow0 + row) * 512 + kb * 64 + kg * 8,
              &Abuf[(size_t)(i * 256 + wid * 64) * 8]);
    }
#pragma unroll
    for (int i = 0; i < 8; i++) {             // B tile (256 x 64): 2048 chunks
      int c = tid + i * 256;
      int row = c >> 3, q = c & 7;
      int kg = q ^ (row & 7);
      async16(b1p + (size_t)row * 512 + kb * 64 + kg * 8,
              &Bbuf[(size_t)(i * 256 + wid * 64) * 8]);
    }
    __syncthreads();
#pragma unroll
    for (int kk = 0; kk < 64; kk += 32) {
      bf16x8 af[4], bfr[4];
      int kc = (kk >> 3) + (lane >> 4);
#pragma unroll
      for (int mt = 0; mt < 4; mt++) {
        int row = mt * 16 + (lane & 15);
        af[mt] = *(const bf16x8*)(&Abuf[(row * 8 + (kc ^ (row & 7))) * 8]);
      }
#pragma unroll
      for (int nt = 0; nt < 4; nt++) {
        int row = wid * 64 + nt * 16 + (lane & 15);
        bfr[nt] = *(const bf16x8*)(&Bbuf[(row * 8 + (kc ^ (row & 7))) * 8]);
      }
#pragma unroll
      for (int mt = 0; mt < 4; mt++)
#pragma unroll
        for (int nt = 0; nt < 4; nt++)
          acc[mt][nt] = __builtin_amdgcn_mfma_f32_16x16x32_bf16(af[mt], bfr[nt], acc[mt][nt], 0, 0, 0);
    }
    __syncthreads();
  }

  // epilogue 1 -> h2 LDS, XOR-swizzled 16B chunks: pos = row*32 + (kc^(row&7))
#pragma unroll
  for (int mt = 0; mt < 4; mt++) {
#pragma unroll
    for (int nt = 0; nt < 4; nt++) {
      int col = wid * 64 + nt * 16 + (lane & 15);
      float bv = bias1[sc * 256 + col];
#pragma unroll
      for (int r = 0; r < 4; r++) {
        int row = mt * 16 + (lane >> 4) * 4 + r;
        float v = fmaxf(acc[mt][nt][r] + bv, 0.f);
        h2[(row * 32 + ((col >> 3) ^ (row & 7))) * 8 + (col & 7)] = f2bf(v);
      }
    }
  }

  // ---- phase 2: L2 (64 x 64, K=256); stage full sT2 slice (32 KB) once ----
  const ushort* b2p = sT2 + (size_t)sc * 64 * 256;
#pragma unroll
  for (int i = 0; i < 8; i++) {               // 64 rows x 32 chunks
    int p = tid + i * 256;
    int row = p >> 5, pc = p & 31;
    int kg = pc ^ (row & 7);
    async16(b2p + (size_t)row * 256 + kg * 8,
            &Bbuf[(size_t)(i * 256 + wid * 64) * 8]);
  }
  __syncthreads();

  f32x4 acc2[4];
#pragma unroll
  for (int nt = 0; nt < 4; nt++) acc2[nt] = (f32x4){0.f, 0.f, 0.f, 0.f};

#pragma unroll
  for (int kk = 0; kk < 256; kk += 32) {
    int kf = (kk >> 3) + (lane >> 4);
    bf16x8 af;
    {
      int row = wid * 16 + (lane & 15);       // wave owns 16 output rows
      af = *(const bf16x8*)(&h2[(row * 32 + (kf ^ (row & 7))) * 8]);
    }
    bf16x8 bfr[4];
#pragma unroll
    for (int nt = 0; nt < 4; nt++) {
      int n = nt * 16 + (lane & 15);
      bfr[nt] = *(const bf16x8*)(&Bbuf[(n * 32 + (kf ^ (n & 7))) * 8]);
    }
#pragma unroll
    for (int nt = 0; nt < 4; nt++)
      acc2[nt] = __builtin_amdgcn_mfma_f32_16x16x32_bf16(af, bfr[nt], acc2[nt], 0, 0, 0);
  }

  // epilogue 2: scatter fp32 rows via idxp; pad rows (>= maxloc) skipped
  int rowg[4], gidx[4];
#pragma unroll
  for (int r = 0; r < 4; r++) {
    rowg[r] = mrow0 + wid * 16 + (lane >> 4) * 4 + r;
    gidx[r] = idxp[rowg[r]];
  }
#pragma unroll
  for (int nt = 0; nt < 4; nt++) {
    int col = nt * 16 + (lane & 15);
    float bv = bias2[sc * 64 + col];
#pragma unroll
    for (int r = 0; r < 4; r++) {
      if (rowg[r] < maxloc) out[(size_t)gidx[r] * 64 + col] = acc2[nt][r] + bv;
    }
  }
}

extern "C" void kernel_launch(void* const* d_in, const int* in_sizes, int n_in,
                              void* d_out, int out_size, void* d_ws, size_t ws_size,
                              hipStream_t stream) {
  const float* x   = (const float*)d_in[0];
  const int* scene = (const int*)d_in[1];
  const float* W0  = (const float*)d_in[2];
  const float* b0  = (const float*)d_in[3];
  const float* gW0 = (const float*)d_in[4];
  const float* gb0 = (const float*)d_in[5];
  const float* W1  = (const float*)d_in[6];
  const float* b1  = (const float*)d_in[7];
  const float* gW1 = (const float*)d_in[8];
  const float* gb1 = (const float*)d_in[9];
  const float* W2  = (const float*)d_in[10];
  const float* b2  = (const float*)d_in[11];
  const float* gW2 = (const float*)d_in[12];
  const float* gb2 = (const float*)d_in[13];
  float* out = (float*)d_out;

  char* ws = (char*)d_ws;
  size_t off = 0;
  auto alloc = [&](size_t bytes) -> void* {
    void* p = ws + off;
    off = (off + bytes + 255) & ~(size_t)255;
    return p;
  };
  ushort* sT0   = (ushort*)alloc((size_t)7 * 512 * 512 * 2);
  ushort* sT1   = (ushort*)alloc((size_t)7 * 256 * 512 * 2);
  ushort* sT2   = (ushort*)alloc((size_t)7 * 64 * 256 * 2);
  float*  bias0 = (float*)alloc(7 * 512 * 4);
  float*  bias1 = (float*)alloc(7 * 256 * 4);
  float*  bias2 = (float*)alloc(7 * 64 * 4);
  int*    bcnt  = (int*)alloc(NBLK * NSCENE * 4);
  int*    rank  = (int*)alloc(BATCH * 4);
  int*    idxp  = (int*)alloc(PADMAX * 4);
  ushort* xc    = (ushort*)alloc((size_t)PADMAX * 512 * 2);
  ushort* hc1   = (ushort*)alloc((size_t)PADMAX * 512 * 2);
  (void)ws_size; (void)n_in; (void)in_sizes; (void)out_size;

  prep_k<<<NB_W0 + NB_W1 + NB_W2 + NB_BIAS + NB_CNT, 256, 0, stream>>>(
      W0, gW0, W1, gW1, W2, gW2, b0, gb0, b1, gb1, b2, gb2, scene,
      sT0, sT1, sT2, bias0, bias1, bias2, bcnt, rank);
  xc_k<<<BATCH / 8, 256, 0, stream>>>(x, scene, rank, bcnt, idxp, xc);

  gemm0_k<<<dim3(MT_MAX * 2, 4), 256, 0, stream>>>(xc, sT0, bias0, bcnt, hc1);
  gemm12_k<<<dim3(MT_MAX * 2), 256, 0, stream>>>(hc1, sT1, sT2, bias1, bias2,
                                                 bcnt, idxp, out);
}